// Round 16
// baseline (420.877 us; speedup 1.0000x reference)
//
#include <hip/hip_runtime.h>
#include <hip/hip_bf16.h>
#include <math.h>

#define NODES 73728   // B*T*N = 128*64*9
#define BB    128
#define TT    64
#define NN    9
#define LDX   256
#define E_REAL 203648.0f
#define NARR  33

typedef _Float16 half8 __attribute__((ext_vector_type(8)));
typedef _Float16 half4 __attribute__((ext_vector_type(4)));
typedef float f32x4 __attribute__((ext_vector_type(4)));

__device__ __forceinline__ float bfdec(unsigned short u) {
  return __uint_as_float(((unsigned)u) << 16);
}
__device__ __forceinline__ unsigned short f2h(float x) {
  _Float16 h = (_Float16)x;
  return __builtin_bit_cast(unsigned short, h);
}

// 2-wide f16 dot with f32 accumulator (v_dot2_f32_f16)
#if __has_builtin(__builtin_amdgcn_fdot2)
#define DOT2(a, b, c) __builtin_amdgcn_fdot2((a), (b), (c), false)
#else
#define DOT2(a, b, c) ((c) + (float)(a)[0] * (float)(b)[0] + (float)(a)[1] * (float)(b)[1])
#endif
#define D2(v, k) __builtin_shufflevector((v), (v), 2 * (k), 2 * (k) + 1)

#define MFMA16(a, b, c) __builtin_amdgcn_mfma_f32_16x16x32_f16((a), (b), (c), 0, 0, 0)
#define SB0() __builtin_amdgcn_sched_barrier(0)

// async global->LDS, 16B per lane (dest = wave-uniform base + lane*16; SRC is per-lane)
__device__ __forceinline__ void gl_lds16(const _Float16* g, _Float16* l) {
  __builtin_amdgcn_global_load_lds(
      (const __attribute__((address_space(1))) void*)g,
      (__attribute__((address_space(3))) void*)l, 16, 0, 0);
}

// ---------------- dtype detector + fill (one block; fill converts inline from raw) ----------------
__global__ __launch_bounds__(256) void detect_fill_kernel(const unsigned short* __restrict__ raw,
                                                          float* __restrict__ flag,
                                                          float* __restrict__ fill) {
  __shared__ float sx[256], sy[256], sz[256];
  int tid = threadIdx.x;
  float mx = 0.f;
  for (int i = tid; i < 2048; i += 256) mx = fmaxf(mx, fabsf(bfdec(raw[2 * i])));
  sx[tid] = mx;
  __syncthreads();
  for (int s = 128; s > 0; s >>= 1) {
    if (tid < s) sx[tid] = fmaxf(sx[tid], sx[tid + s]);
    __syncthreads();
  }
  bool isf32 = sx[0] > 1000.f;
  if (tid == 0) flag[0] = isf32 ? 1.f : 0.f;
  __syncthreads();                                  // sx reuse below
  const float* rf = (const float*)raw;
  float ax = 0.f, ay = 0.f, az = 0.f;
  for (int p = tid; p < BB * NN; p += 256) {
    int b = p / NN, n = p - b * NN;
    size_t late  = (((size_t)b * TT + (TT - 1)) * NN + n) * 10;
    size_t early = (((size_t)b * TT) * NN + n) * 10;
#pragma unroll
    for (int i = 0; i < 3; i++) {
      float lv = isf32 ? rf[late + i]  : bfdec(raw[late + i]);
      float ev = isf32 ? rf[early + i] : bfdec(raw[early + i]);
      float d = lv - ev;
      if (i == 0) ax += d; else if (i == 1) ay += d; else az += d;
    }
  }
  sx[tid] = ax; sy[tid] = ay; sz[tid] = az;
  __syncthreads();
  for (int s = 128; s > 0; s >>= 1) {
    if (tid < s) { sx[tid] += sx[tid + s]; sy[tid] += sy[tid + s]; sz[tid] += sz[tid + s]; }
    __syncthreads();
  }
  if (tid == 0) { fill[0] = sx[0] / E_REAL; fill[1] = sy[0] / E_REAL; fill[2] = sz[0] / E_REAL; }
}

// ---------------- convert all inputs to fp32 + f16 shadow in ONE pass ----------------
struct CvtArgs { const void* src[NARR]; int size[NARR]; int off[NARR]; };

__global__ __launch_bounds__(256) void convert_kernel(CvtArgs a, const float* __restrict__ flag,
                                                      float* __restrict__ dst,
                                                      _Float16* __restrict__ dsth) {
  int i = blockIdx.y;
  int sz = a.size[i];
  bool isf32 = flag[0] > 0.5f;
  const float* sf = (const float*)a.src[i];
  const unsigned short* sh = (const unsigned short*)a.src[i];
  float* d = dst + a.off[i];
  _Float16* dh = dsth + a.off[i];
  for (int j = blockIdx.x * 256 + threadIdx.x; j < sz; j += gridDim.x * 256) {
    float v = isf32 ? sf[j] : bfdec(sh[j]);
    d[j] = v;
    dh[j] = (_Float16)v;
  }
}

// ================= single per-layer kernel: triple GEMM {lW,rW,sW}, K compile-time =================
// Block: 32 own rows x 256 cols, 8 waves (512 thr); wave wv owns cols [wv*32, wv*32+32).
// R13-proven loop: A resides in LDS (3 tiles: gather + 2 own, XOR-chunk format); B staged
// per-wave (fixed slot per matrix, stage-after-consume, <=2 live B-frags), 3 counted waits/step
// (B-only queue, all vmcnt(4); tail 4/2/0), full K-unroll.
// ENC (layer 0): encoder computed IN-BLOCK into the A tiles (R15-vectorized inner loop).
// R16: (1) layer-2 skips the dead Xout store (only the pool is consumed downstream);
//      (2) nf halo rows (xyz only) staged into a persistent LDS region in the prologue
//          (one masked gl_lds wave-op) — edge phase reads LDS, not global.
// A-chunk layout (chunk c = t*3+tl, 512 halfs = 16 rows x 32 k):
//   stored (row p, slot q) holds source k-chunk q ^ ((p>>1)&3); read slot = quad ^ ((mrow>>1)&3).
// Gather tile: row p<=8 -> node row0-9+p (clamped), p>=9 -> row0+32; garbage masked by edge
// validity; epilogue scatters gather outputs (p==9 -> xl[48], p>9 -> scratch 49).
template <int K, bool ENC>
__global__ __launch_bounds__(512, 4) void fused3_kernel(
    const _Float16* __restrict__ Xin, _Float16* __restrict__ Xout,
    const _Float16* __restrict__ lW, const float* __restrict__ lb,
    const _Float16* __restrict__ rW, const float* __restrict__ rb,
    const _Float16* __restrict__ sW, const float* __restrict__ sb,
    const float* __restrict__ nf, const float* __restrict__ fill,
    const _Float16* __restrict__ atth, const _Float16* __restrict__ ewh,
    const float* __restrict__ gamma, const float* __restrict__ beta,
    float* pool_out, int do_pool,
    const float* __restrict__ encW, const float* __restrict__ encb) {
  constexpr int NK = K >> 5;                    // 4 or 8
  __shared__ union {
    struct {
      _Float16 B[8 * 3072];                     // 8 waves * 3 slots * 1024 halfs = 48 KB
      _Float16 A[3 * NK * 512];                 // 3 tiles * NK steps * (16 rows x 32 k) chunks
    } loop;                                     // 72 KB (K=256) / 60 KB (K=128)
    struct {
      unsigned short xl[50][264];               // xl[i] = XL row (row0-16+i); 7..48 used; 49=scratch
      unsigned short epi[32][264];              // XR -> AGG -> XO (in place)
    } s;
    float pacc[8][256];                         // overlays loop region (dead after K-loop)
  } sh;
  __shared__ float nfl[42][4];                  // persistent: nf xyz for rows row0-9 .. row0+32
  int tid = threadIdx.x;
  int row0 = blockIdx.x * 32;
  const int lane = tid & 63, wv = tid >> 6;
  const int quad = lane >> 4, mrow = lane & 15;
  const int bchunk = (lane & 3) ^ ((lane >> 3) & 3);   // staging src chunk (XOR swizzle)
  const int rchunk = quad ^ ((mrow >> 1) & 3);         // read chunk (same involution)
  _Float16* ring = sh.loop.B + wv * 3072;              // B slot m at ring + m*1024
  _Float16* Ald  = sh.loop.A;
  const size_t wcol = (size_t)(wv * 32 + (lane >> 2));
  constexpr size_t wstep = (size_t)16 * K;
  const _Float16* lsrc  = lW + wcol * K + bchunk * 8;
  const _Float16* lsrc2 = lsrc + wstep;
  const _Float16* rsrc  = rW + wcol * K + bchunk * 8;
  const _Float16* rsrc2 = rsrc + wstep;
  const _Float16* ssrc  = sW + wcol * K + bchunk * 8;
  const _Float16* ssrc2 = ssrc + wstep;

  f32x4 accL[3][2] = {};
  f32x4 accR[2][2] = {};
  f32x4 accS[2][2] = {};

  // ---- prologue: B step-0 first (latency hides under ENC/A-staging), nf halo, then A ----
  gl_lds16(lsrc, ring);        gl_lds16(lsrc2, ring + 512);
  gl_lds16(rsrc, ring + 1024); gl_lds16(rsrc2, ring + 1536);
  gl_lds16(ssrc, ring + 2048); gl_lds16(ssrc2, ring + 2560);
  if (wv == 0 && lane < 42) {                   // 42 nf halo rows, 16B each (xyz + 1 extra)
    int r = row0 - 9 + lane;
    r = r < 0 ? 0 : (r >= NODES ? NODES - 1 : r);
    gl_lds16((const _Float16*)(nf + (size_t)r * 10), (_Float16*)&nfl[0][0]);
  }
  if constexpr (ENC) {
    // each slot = (chunk c, lane-within-chunk l): 8 dims of one row, written in tile format
    for (int slot = tid; slot < 3 * NK * 64; slot += 512) {
      int c = slot >> 6, l = slot & 63;
      int t = c / 3, tl = c - t * 3;
      int p = l >> 2, q = l & 3;
      int d0 = t * 32 + ((q ^ ((p >> 1) & 3)) << 3);   // source dims (inverse of read involution)
      int node;
      if (tl == 0)      node = (p <= 8) ? (row0 - 9 + p) : (row0 + 32);
      else if (tl == 1) node = row0 + p;
      else              node = row0 + 16 + p;
      node = node < 0 ? 0 : (node >= NODES ? NODES - 1 : node);
      int n = node % NN;
      float f[14];
      const float2* nf2 = (const float2*)(nf + (size_t)node * 10);
#pragma unroll
      for (int i = 0; i < 5; i++) { float2 v = nf2[i]; f[2 * i] = v.x; f[2 * i + 1] = v.y; }
      f[10] = (n < 7) ? 1.f : 0.f;
      f[11] = (n == 7) ? 1.f : 0.f;
      f[12] = (n == 8) ? 1.f : 0.f;
      f[13] = fabsf((float)(n - 7));
      float acc8[8];
      {
        float4 b0 = *(const float4*)&encb[n * 128 + d0];
        float4 b1 = *(const float4*)&encb[n * 128 + d0 + 4];
        acc8[0] = b0.x; acc8[1] = b0.y; acc8[2] = b0.z; acc8[3] = b0.w;
        acc8[4] = b1.x; acc8[5] = b1.y; acc8[6] = b1.z; acc8[7] = b1.w;
      }
      // 8 rows x 14 = 112 contiguous floats, 16B-aligned (d0 multiple of 8)
      const float4* w4 = (const float4*)&encW[((size_t)n * 128 + d0) * 14];
#pragma unroll
      for (int j = 0; j < 28; j++) {
        float4 w = w4[j];
        acc8[(4 * j + 0) / 14] = fmaf(f[(4 * j + 0) % 14], w.x, acc8[(4 * j + 0) / 14]);
        acc8[(4 * j + 1) / 14] = fmaf(f[(4 * j + 1) % 14], w.y, acc8[(4 * j + 1) / 14]);
        acc8[(4 * j + 2) / 14] = fmaf(f[(4 * j + 2) % 14], w.z, acc8[(4 * j + 2) / 14]);
        acc8[(4 * j + 3) / 14] = fmaf(f[(4 * j + 3) % 14], w.w, acc8[(4 * j + 3) / 14]);
      }
      half8 o;
#pragma unroll
      for (int j = 0; j < 8; j++) o[j] = (_Float16)acc8[j];
      *(half8*)(Ald + c * 512 + p * 32 + q * 8) = o;
    }
  } else {
    int p = lane >> 2;                                  // row within tile
    int gnode = (p <= 8) ? (row0 - 9 + p) : (row0 + 32);
    gnode = gnode < 0 ? 0 : (gnode >= NODES ? NODES - 1 : gnode);
    int on0 = row0 + p;
    int on1 = row0 + 16 + p; on1 = on1 >= NODES ? NODES - 1 : on1;
#pragma unroll
    for (int i = 0; i < 3; i++) {
      int c = wv + i * 8;                               // chunk id = t*3 + tl
      if (c < 3 * NK) {                                 // wave-uniform branch
        int t = c / 3, tl = c - t * 3;
        int node = (tl == 0) ? gnode : ((tl == 1) ? on0 : on1);
        gl_lds16(Xin + (size_t)node * LDX + t * 32 + bchunk * 8, Ald + c * 512);
      }
    }
  }
  __syncthreads();             // drains own gl_lds + A/nfl visible to all waves

#pragma unroll
  for (int t = 0; t < NK; t++) {
    const bool more = (t + 1 < NK);             // compile-time under full unroll
    const int kn = (t + 1) << 5;                // folds into load immediates
    // A fragments from LDS — issue BEFORE w1 so ds_read latency hides under the wait
    const _Float16* abase = Ald + (t * 3) * 512 + mrow * 32 + rchunk * 8;
    half8 a0 = *(const half8*)abase;            // gather tile
    half8 a1 = *(const half8*)(abase + 512);    // own rows row0..+15
    half8 a2 = *(const half8*)(abase + 1024);   // own rows row0+16..+31
    SB0();
    asm volatile("s_waitcnt vmcnt(4)" ::: "memory");   // L_t landed (B-only queue)
    SB0();
    {  // L group (6 MFMA)
      half8 b0 = *(const half8*)&ring[(0 * 16 + mrow) * 32 + rchunk * 8];
      half8 b1 = *(const half8*)&ring[(1 * 16 + mrow) * 32 + rchunk * 8];
      accL[0][0] = MFMA16(a0, b0, accL[0][0]);
      accL[0][1] = MFMA16(a0, b1, accL[0][1]);
      accL[1][0] = MFMA16(a1, b0, accL[1][0]);
      accL[1][1] = MFMA16(a1, b1, accL[1][1]);
      accL[2][0] = MFMA16(a2, b0, accL[2][0]);
      accL[2][1] = MFMA16(a2, b1, accL[2][1]);
    }
    SB0();
    if (more) { gl_lds16(lsrc + kn, ring); gl_lds16(lsrc2 + kn, ring + 512); }
    SB0();
    if (more) asm volatile("s_waitcnt vmcnt(4)" ::: "memory");   // R_t landed
    else      asm volatile("s_waitcnt vmcnt(2)" ::: "memory");
    SB0();
    {  // R group (4 MFMA) — own tiles
      const _Float16* bb = ring + 1024;
      half8 b0 = *(const half8*)&bb[(0 * 16 + mrow) * 32 + rchunk * 8];
      half8 b1 = *(const half8*)&bb[(1 * 16 + mrow) * 32 + rchunk * 8];
      accR[0][0] = MFMA16(a1, b0, accR[0][0]);
      accR[1][0] = MFMA16(a2, b0, accR[1][0]);
      accR[0][1] = MFMA16(a1, b1, accR[0][1]);
      accR[1][1] = MFMA16(a2, b1, accR[1][1]);
    }
    SB0();
    if (more) { gl_lds16(rsrc + kn, ring + 1024); gl_lds16(rsrc2 + kn, ring + 1536); }
    SB0();
    if (more) asm volatile("s_waitcnt vmcnt(4)" ::: "memory");   // S_t landed
    else      asm volatile("s_waitcnt vmcnt(0)" ::: "memory");
    SB0();
    {  // S group (4 MFMA) — own tiles
      const _Float16* bb = ring + 2048;
      half8 b0 = *(const half8*)&bb[(0 * 16 + mrow) * 32 + rchunk * 8];
      half8 b1 = *(const half8*)&bb[(1 * 16 + mrow) * 32 + rchunk * 8];
      accS[0][0] = MFMA16(a1, b0, accS[0][0]);
      accS[1][0] = MFMA16(a2, b0, accS[1][0]);
      accS[0][1] = MFMA16(a1, b1, accS[0][1]);
      accS[1][1] = MFMA16(a2, b1, accS[1][1]);
    }
    SB0();
    if (more) { gl_lds16(ssrc + kn, ring + 2048); gl_lds16(ssrc2 + kn, ring + 2560); }
    SB0();
  }

  __syncthreads();                     // loop region dead; xl/epi overlay it

  // ---- epilogue writes: accL(+lb) -> xl (scattered), accR(+rb) -> epi ----
  {
    int quad_ = lane >> 4, mrow_ = lane & 15;
#pragma unroll
    for (int tl = 0; tl < 3; tl++)
#pragma unroll
      for (int ct = 0; ct < 2; ct++) {
        int col = wv * 32 + ct * 16 + mrow_;
        float bs = lb[col];
#pragma unroll
        for (int r = 0; r < 4; r++) {
          int p = quad_ * 4 + r;       // output position within tile = A row index
          int xlrow;
          if (tl == 0) xlrow = (p <= 8) ? (p + 7) : ((p == 9) ? 48 : 49);  // 49 = scratch
          else         xlrow = tl * 16 + p;      // tl=1 -> 16..31, tl=2 -> 32..47
          sh.s.xl[xlrow][col] = f2h(accL[tl][ct][r] + bs);
        }
      }
#pragma unroll
    for (int rt = 0; rt < 2; rt++)
#pragma unroll
      for (int ct = 0; ct < 2; ct++) {
        int col = wv * 32 + ct * 16 + mrow_;
        float bs = rb[col];
#pragma unroll
        for (int r = 0; r < 4; r++)
          sh.s.epi[rt * 16 + quad_ * 4 + r][col] = f2h(accR[rt][ct][r] + bs);
      }
  }
  __syncthreads();

  // ---- edge phase: logits + softmax + aggregation (AGG overwrites epi in place) ----
  {
    int g = lane >> 4;          // wave handles row r = wv*4 + g
    int l = lane & 15;          // 16-channel slab per lane
    int ch0 = l << 4;
    half8 att_lo = *(const half8*)&atth[ch0];
    half8 att_hi = *(const half8*)&atth[ch0 + 8];
    half8 ew0l, ew1l, ew2l, ew0h, ew1h, ew2h;
#pragma unroll
    for (int j = 0; j < 8; j++) {
      ew0l[j] = ewh[(ch0 + j) * 3 + 0];      ew0h[j] = ewh[(ch0 + 8 + j) * 3 + 0];
      ew1l[j] = ewh[(ch0 + j) * 3 + 1];      ew1h[j] = ewh[(ch0 + 8 + j) * 3 + 1];
      ew2l[j] = ewh[(ch0 + j) * 3 + 2];      ew2h[j] = ewh[(ch0 + 8 + j) * 3 + 2];
    }
    float f0 = fill[0], f1 = fill[1], f2 = fill[2];
    int r = wv * 4 + g;
    int v = row0 + r;
    int n = v % NN;
    int t = (v / NN) & 63;
    // nfl index for node s = s - row0 + 9 (staged rows row0-9 .. row0+32)
    int srcs[4]  = { v, (n > 0) ? v - 1 : v, (n < NN - 1) ? v + 1 : v, (t > 0) ? v - NN : v };
    int sidx[4]  = { r + 9, (n > 0) ? r + 8 : r + 9, (n < NN - 1) ? r + 10 : r + 9,
                     (t > 0) ? r : r + 9 };
    bool valid[4] = { true, n > 0, n < NN - 1, t > 0 };
    float px = nfl[r + 9][0];
    float py = nfl[r + 9][1];
    float pz = nfl[r + 9][2];
    _Float16* erow = (_Float16*)sh.s.epi[r];
    half8 xr_lo = *(const half8*)&erow[ch0];
    half8 xr_hi = *(const half8*)&erow[ch0 + 8];
    half8 xls[4][2];
    float lg[4];
#pragma unroll
    for (int e = 0; e < 4; e++) {
      int s = srcs[e];
      float a0, a1, a2;
      if (e == 0) { a0 = f0; a1 = f1; a2 = f2; }
      else {
        a0 = px - nfl[sidx[e]][0];
        a1 = py - nfl[sidx[e]][1];
        a2 = pz - nfl[sidx[e]][2];
      }
      _Float16 h0 = (_Float16)a0, h1 = (_Float16)a1, h2 = (_Float16)a2;
      const _Float16* xrow = (const _Float16*)sh.s.xl[s - row0 + 16];   // indices 7..48
      xls[e][0] = *(const half8*)&xrow[ch0];
      xls[e][1] = *(const half8*)&xrow[ch0 + 8];
      half8 mlo = (xr_lo + xls[e][0]) + (ew0l * h0 + ew1l * h1 + ew2l * h2);
      half8 mhi = (xr_hi + xls[e][1]) + (ew0h * h0 + ew1h * h1 + ew2h * h2);
      mlo = __builtin_elementwise_max(mlo, mlo * (_Float16)0.2f);   // leaky 0.2 exact
      mhi = __builtin_elementwise_max(mhi, mhi * (_Float16)0.2f);
      float p = 0.f;
      p = DOT2(D2(mlo, 0), D2(att_lo, 0), p);
      p = DOT2(D2(mlo, 1), D2(att_lo, 1), p);
      p = DOT2(D2(mlo, 2), D2(att_lo, 2), p);
      p = DOT2(D2(mlo, 3), D2(att_lo, 3), p);
      p = DOT2(D2(mhi, 0), D2(att_hi, 0), p);
      p = DOT2(D2(mhi, 1), D2(att_hi, 1), p);
      p = DOT2(D2(mhi, 2), D2(att_hi, 2), p);
      p = DOT2(D2(mhi, 3), D2(att_hi, 3), p);
      p += __shfl_xor(p, 1);        // head spans 4 lanes (64 ch)
      p += __shfl_xor(p, 2);
      lg[e] = valid[e] ? p : -1e30f;
    }
    float mx = fmaxf(fmaxf(lg[0], lg[1]), fmaxf(lg[2], lg[3]));
    float w0 = __expf(lg[0] - mx), w1 = __expf(lg[1] - mx);
    float w2 = __expf(lg[2] - mx), w3 = __expf(lg[3] - mx);
    float inv = 1.f / (w0 + w1 + w2 + w3);
    float wv4[4] = { w0, w1, w2, w3 };
    half8 agg_lo = { 0, 0, 0, 0, 0, 0, 0, 0 };
    half8 agg_hi = { 0, 0, 0, 0, 0, 0, 0, 0 };
#pragma unroll
    for (int e = 0; e < 4; e++) {
      _Float16 wh = (_Float16)(wv4[e] * inv);   // invalid edges: exactly 0
      agg_lo = agg_lo + xls[e][0] * wh;
      agg_hi = agg_hi + xls[e][1] * wh;
    }
    // in-place: this lane is the only reader/writer of this slab
    *(half8*)&erow[ch0] = agg_lo;
    *(half8*)&erow[ch0 + 8] = agg_hi;
  }
  __syncthreads();                      // AGG visible to all waves

  // ---- phase 3: epi = accS + sb + AGG (in place) ----
  {
    int quad_ = lane >> 4, mrow_ = lane & 15;
#pragma unroll
    for (int rt = 0; rt < 2; rt++)
#pragma unroll
      for (int ct = 0; ct < 2; ct++) {
        int col = wv * 32 + ct * 16 + mrow_;
        float bs = sb[col];
#pragma unroll
        for (int rr = 0; rr < 4; rr++) {
          int row = rt * 16 + quad_ * 4 + rr;
          _Float16 ag = *(const _Float16*)&sh.s.epi[row][col];
          sh.s.epi[row][col] = f2h(accS[rt][ct][rr] + bs + (float)ag);
        }
      }
  }
  __syncthreads();

  // ---- phase 4: LayerNorm + SiLU + write Xout (skipped for final layer) (+ pool) ----
  {
    int cc = lane << 2;
    float gm[4], bt[4];
#pragma unroll
    for (int i = 0; i < 4; i++) { gm[i] = gamma[cc + i]; bt[i] = beta[cc + i]; }
    float psum[4] = { 0.f, 0.f, 0.f, 0.f };
    for (int k = 0; k < 4; k++) {
      int r = wv * 4 + k;
      int v = row0 + r;
      const _Float16* erow = (const _Float16*)sh.s.epi[r];
      half4 x4 = *(const half4*)&erow[cc];
      float xv[4] = { (float)x4[0], (float)x4[1], (float)x4[2], (float)x4[3] };
      float s1 = xv[0] + xv[1] + xv[2] + xv[3];
#pragma unroll
      for (int off = 1; off < 64; off <<= 1) s1 += __shfl_xor(s1, off);
      float mu = s1 * (1.f / 256.f);
      float s2 = 0.f;
#pragma unroll
      for (int i = 0; i < 4; i++) { float d = xv[i] - mu; s2 = fmaf(d, d, s2); }
#pragma unroll
      for (int off = 1; off < 64; off <<= 1) s2 += __shfl_xor(s2, off);
      float rs = rsqrtf(s2 * (1.f / 256.f) + 1e-5f);
      half4 o;
#pragma unroll
      for (int i = 0; i < 4; i++) {
        float y = (xv[i] - mu) * rs * gm[i] + bt[i];
        float z = y * (1.f / (1.f + __expf(-y)));   // SiLU
        o[i] = (_Float16)z;
        psum[i] += z;
      }
      if (!do_pool)                      // final layer: X is only consumed via the pool
        *(half4*)&Xout[(size_t)v * LDX + cc] = o;
    }
    if (do_pool) {
      __syncthreads();                 // epi reads done; pacc overlays loop region (dead)
#pragma unroll
      for (int i = 0; i < 4; i++) sh.pacc[wv][cc + i] = psum[i];
      __syncthreads();
      if (wv == 0) {
        int b = row0 / 576;            // 576 = 9*64: block fully within one batch
#pragma unroll
        for (int i = 0; i < 4; i++) {
          float s = 0.f;
#pragma unroll
          for (int w = 0; w < 8; w++) s += sh.pacc[w][cc + i];
          atomicAdd(&pool_out[b * 256 + cc + i], s * (1.f / 576.f));
        }
      }
    }
  }
}

extern "C" void kernel_launch(void* const* d_in, const int* in_sizes, int n_in,
                              void* d_out, int out_size, void* d_ws, size_t ws_size,
                              hipStream_t stream) {
  static const int kSize[NARR] = {
    737280, 16128, 1152,
    32768, 256, 32768, 256, 256, 768, 32768, 256, 256, 256,   // layer 0 (K=128)
    65536, 256, 65536, 256, 256, 768, 65536, 256, 256, 256,   // layer 1 (K=256)
    65536, 256, 65536, 256, 256, 768, 65536, 256, 256, 256    // layer 2 (K=256)
  };
  if (n_in != NARR || out_size != BB * 256) return;
  for (int i = 0; i < NARR; i++) if (in_sizes[i] != kSize[i]) return;

  CvtArgs ca;
  int off = 0;
  for (int i = 0; i < NARR; i++) { ca.src[i] = d_in[i]; ca.size[i] = kSize[i]; ca.off[i] = off; off += kSize[i]; }
  const int PRM_ELEMS = off;   // 1,252,992

  const size_t OFF_FLAG = 0;
  const size_t OFF_FILL = 16;
  const size_t OFF_PRM  = 256;
  const size_t OFF_PRMH = OFF_PRM + (size_t)PRM_ELEMS * 4;     // f16 shadow
  const size_t OFF_X0   = OFF_PRMH + (size_t)PRM_ELEMS * 2;    // X ping
  const size_t OFF_X1   = OFF_X0 + (size_t)NODES * LDX * 2;    // X pong
  const size_t NEED     = OFF_X1 + (size_t)NODES * LDX * 2;    // ~83 MiB
  if (ws_size < NEED) return;

  char* ws = (char*)d_ws;
  float*     flag = (float*)(ws + OFF_FLAG);
  float*     fill = (float*)(ws + OFF_FILL);
  float*     prm  = (float*)(ws + OFF_PRM);
  _Float16*  prmh = (_Float16*)(ws + OFF_PRMH);
  _Float16*  X0   = (_Float16*)(ws + OFF_X0);
  _Float16*  X1   = (_Float16*)(ws + OFF_X1);

  hipMemsetAsync(d_out, 0, (size_t)out_size * 4, stream);   // pool accumulator
  detect_fill_kernel<<<1, 256, 0, stream>>>((const unsigned short*)d_in[0], flag, fill);
  convert_kernel<<<dim3(128, NARR), 256, 0, stream>>>(ca, flag, prm, prmh);

  const float* nf   = prm + ca.off[0];
  const float* encW = prm + ca.off[1];
  const float* encb = prm + ca.off[2];

  for (int L = 0; L < 3; L++) {
    const _Float16* lWh = prmh + ca.off[3 + L * 10 + 0];
    const float*    lb  = prm  + ca.off[3 + L * 10 + 1];
    const _Float16* rWh = prmh + ca.off[3 + L * 10 + 2];
    const float*    rb  = prm  + ca.off[3 + L * 10 + 3];
    const _Float16* atth= prmh + ca.off[3 + L * 10 + 4];
    const _Float16* ewhp= prmh + ca.off[3 + L * 10 + 5];
    const _Float16* sWh = prmh + ca.off[3 + L * 10 + 6];
    const float*    sb  = prm  + ca.off[3 + L * 10 + 7];
    const float*    g   = prm  + ca.off[3 + L * 10 + 8];
    const float*    b   = prm  + ca.off[3 + L * 10 + 9];
    if (L == 0)
      fused3_kernel<128, true><<<NODES / 32, 512, 0, stream>>>(
          X1 /*unused*/, X0, lWh, lb, rWh, rb, sWh, sb, nf, fill, atth, ewhp, g, b,
          (float*)d_out, 0, encW, encb);
    else if (L == 1)
      fused3_kernel<256, false><<<NODES / 32, 512, 0, stream>>>(
          X0, X1, lWh, lb, rWh, rb, sWh, sb, nf, fill, atth, ewhp, g, b,
          (float*)d_out, 0, nullptr, nullptr);
    else
      fused3_kernel<256, false><<<NODES / 32, 512, 0, stream>>>(
          X1, X0, lWh, lb, rWh, rb, sWh, sb, nf, fill, atth, ewhp, g, b,
          (float*)d_out, 1, nullptr, nullptr);
  }
}

// Round 17
// 411.733 us; speedup vs baseline: 1.0222x; 1.0222x over previous
//
#include <hip/hip_runtime.h>
#include <hip/hip_bf16.h>
#include <math.h>

#define NODES 73728   // B*T*N = 128*64*9
#define BB    128
#define TT    64
#define NN    9
#define LDX   256
#define E_REAL 203648.0f
#define NARR  33

typedef _Float16 half8 __attribute__((ext_vector_type(8)));
typedef _Float16 half4 __attribute__((ext_vector_type(4)));
typedef float f32x4 __attribute__((ext_vector_type(4)));

__device__ __forceinline__ float bfdec(unsigned short u) {
  return __uint_as_float(((unsigned)u) << 16);
}
__device__ __forceinline__ unsigned short f2h(float x) {
  _Float16 h = (_Float16)x;
  return __builtin_bit_cast(unsigned short, h);
}

// 2-wide f16 dot with f32 accumulator (v_dot2_f32_f16)
#if __has_builtin(__builtin_amdgcn_fdot2)
#define DOT2(a, b, c) __builtin_amdgcn_fdot2((a), (b), (c), false)
#else
#define DOT2(a, b, c) ((c) + (float)(a)[0] * (float)(b)[0] + (float)(a)[1] * (float)(b)[1])
#endif
#define D2(v, k) __builtin_shufflevector((v), (v), 2 * (k), 2 * (k) + 1)

#define MFMA16(a, b, c) __builtin_amdgcn_mfma_f32_16x16x32_f16((a), (b), (c), 0, 0, 0)
#define SB0() __builtin_amdgcn_sched_barrier(0)

// async global->LDS, 16B per lane (dest = wave-uniform base + lane*16; SRC is per-lane)
__device__ __forceinline__ void gl_lds16(const _Float16* g, _Float16* l) {
  __builtin_amdgcn_global_load_lds(
      (const __attribute__((address_space(1))) void*)g,
      (__attribute__((address_space(3))) void*)l, 16, 0, 0);
}

// ---------------- dtype detector + fill (one block; fill converts inline from raw) ----------------
__global__ __launch_bounds__(256) void detect_fill_kernel(const unsigned short* __restrict__ raw,
                                                          float* __restrict__ flag,
                                                          float* __restrict__ fill) {
  __shared__ float sx[256], sy[256], sz[256];
  int tid = threadIdx.x;
  float mx = 0.f;
  for (int i = tid; i < 2048; i += 256) mx = fmaxf(mx, fabsf(bfdec(raw[2 * i])));
  sx[tid] = mx;
  __syncthreads();
  for (int s = 128; s > 0; s >>= 1) {
    if (tid < s) sx[tid] = fmaxf(sx[tid], sx[tid + s]);
    __syncthreads();
  }
  bool isf32 = sx[0] > 1000.f;
  if (tid == 0) flag[0] = isf32 ? 1.f : 0.f;
  __syncthreads();                                  // sx reuse below
  const float* rf = (const float*)raw;
  float ax = 0.f, ay = 0.f, az = 0.f;
  for (int p = tid; p < BB * NN; p += 256) {
    int b = p / NN, n = p - b * NN;
    size_t late  = (((size_t)b * TT + (TT - 1)) * NN + n) * 10;
    size_t early = (((size_t)b * TT) * NN + n) * 10;
#pragma unroll
    for (int i = 0; i < 3; i++) {
      float lv = isf32 ? rf[late + i]  : bfdec(raw[late + i]);
      float ev = isf32 ? rf[early + i] : bfdec(raw[early + i]);
      float d = lv - ev;
      if (i == 0) ax += d; else if (i == 1) ay += d; else az += d;
    }
  }
  sx[tid] = ax; sy[tid] = ay; sz[tid] = az;
  __syncthreads();
  for (int s = 128; s > 0; s >>= 1) {
    if (tid < s) { sx[tid] += sx[tid + s]; sy[tid] += sy[tid + s]; sz[tid] += sz[tid + s]; }
    __syncthreads();
  }
  if (tid == 0) { fill[0] = sx[0] / E_REAL; fill[1] = sy[0] / E_REAL; fill[2] = sz[0] / E_REAL; }
}

// ---------------- convert all inputs to fp32 + f16 shadow in ONE pass ----------------
struct CvtArgs { const void* src[NARR]; int size[NARR]; int off[NARR]; };

__global__ __launch_bounds__(256) void convert_kernel(CvtArgs a, const float* __restrict__ flag,
                                                      float* __restrict__ dst,
                                                      _Float16* __restrict__ dsth) {
  int i = blockIdx.y;
  int sz = a.size[i];
  bool isf32 = flag[0] > 0.5f;
  const float* sf = (const float*)a.src[i];
  const unsigned short* sh = (const unsigned short*)a.src[i];
  float* d = dst + a.off[i];
  _Float16* dh = dsth + a.off[i];
  for (int j = blockIdx.x * 256 + threadIdx.x; j < sz; j += gridDim.x * 256) {
    float v = isf32 ? sf[j] : bfdec(sh[j]);
    d[j] = v;
    dh[j] = (_Float16)v;
  }
}

// ================= single per-layer kernel: triple GEMM {lW,rW,sW}, K compile-time =================
// Block: 32 own rows x 256 cols, 8 waves (512 thr); wave wv owns cols [wv*32, wv*32+32).
// R13-proven loop: A resides in LDS (3 tiles: gather + 2 own, XOR-chunk format); B staged
// per-wave (fixed slot per matrix, stage-after-consume, <=2 live B-frags), 3 counted waits/step
// (B-only queue, all vmcnt(4); tail 4/2/0), full K-unroll.
// ENC (layer 0): encoder computed IN-BLOCK into the A tiles (R15-vectorized inner loop).
// R17: post-loop restructure. Epilogue writes accS+sb into epi2; the edge phase adds XO to AGG
// (vector f16) and writes the pre-LN value back to epi2 — phase-3 and its barrier deleted.
// Non-pool LN uses edge-phase layout (lane = row-of-4 x 16-ch slab): 8 shfl instead of 48,
// coalesced half8 stores. POOL layer keeps the proven full-wave LN + pool reduction.
template <int K, bool ENC, bool POOL>
__global__ __launch_bounds__(512, 4) void fused3_kernel(
    const _Float16* __restrict__ Xin, _Float16* __restrict__ Xout,
    const _Float16* __restrict__ lW, const float* __restrict__ lb,
    const _Float16* __restrict__ rW, const float* __restrict__ rb,
    const _Float16* __restrict__ sW, const float* __restrict__ sb,
    const float* __restrict__ nf, const float* __restrict__ fill,
    const _Float16* __restrict__ atth, const _Float16* __restrict__ ewh,
    const float* __restrict__ gamma, const float* __restrict__ beta,
    float* pool_out,
    const float* __restrict__ encW, const float* __restrict__ encb) {
  constexpr int NK = K >> 5;                    // 4 or 8
  __shared__ union {
    struct {
      _Float16 B[8 * 3072];                     // 8 waves * 3 slots * 1024 halfs = 48 KB
      _Float16 A[3 * NK * 512];                 // 3 tiles * NK steps * (16 rows x 32 k) chunks
    } loop;
    struct {
      unsigned short xl[50][264];               // xl[i] = XL row (row0-16+i); 7..48 used; 49=scratch
      unsigned short epi[32][264];              // XR
      unsigned short epi2[32][264];             // XO(+sb) -> (+AGG) pre-LN value (in place)
    } s;
    float pacc[8][256];                         // overlays loop region (dead after K-loop)
  } sh;
  __shared__ float nfl[42][4];                  // persistent: nf xyz for rows row0-9 .. row0+32
  int tid = threadIdx.x;
  int row0 = blockIdx.x * 32;
  const int lane = tid & 63, wv = tid >> 6;
  const int quad = lane >> 4, mrow = lane & 15;
  const int bchunk = (lane & 3) ^ ((lane >> 3) & 3);   // staging src chunk (XOR swizzle)
  const int rchunk = quad ^ ((mrow >> 1) & 3);         // read chunk (same involution)
  _Float16* ring = sh.loop.B + wv * 3072;              // B slot m at ring + m*1024
  _Float16* Ald  = sh.loop.A;
  const size_t wcol = (size_t)(wv * 32 + (lane >> 2));
  constexpr size_t wstep = (size_t)16 * K;
  const _Float16* lsrc  = lW + wcol * K + bchunk * 8;
  const _Float16* lsrc2 = lsrc + wstep;
  const _Float16* rsrc  = rW + wcol * K + bchunk * 8;
  const _Float16* rsrc2 = rsrc + wstep;
  const _Float16* ssrc  = sW + wcol * K + bchunk * 8;
  const _Float16* ssrc2 = ssrc + wstep;

  f32x4 accL[3][2] = {};
  f32x4 accR[2][2] = {};
  f32x4 accS[2][2] = {};

  // ---- prologue: B step-0 first (latency hides under ENC/A-staging), nf halo, then A ----
  gl_lds16(lsrc, ring);        gl_lds16(lsrc2, ring + 512);
  gl_lds16(rsrc, ring + 1024); gl_lds16(rsrc2, ring + 1536);
  gl_lds16(ssrc, ring + 2048); gl_lds16(ssrc2, ring + 2560);
  if (wv == 0 && lane < 42) {                   // 42 nf halo rows, 16B each (xyz + 1 extra)
    int r = row0 - 9 + lane;
    r = r < 0 ? 0 : (r >= NODES ? NODES - 1 : r);
    gl_lds16((const _Float16*)(nf + (size_t)r * 10), (_Float16*)&nfl[0][0]);
  }
  if constexpr (ENC) {
    // each slot = (chunk c, lane-within-chunk l): 8 dims of one row, written in tile format
    for (int slot = tid; slot < 3 * NK * 64; slot += 512) {
      int c = slot >> 6, l = slot & 63;
      int t = c / 3, tl = c - t * 3;
      int p = l >> 2, q = l & 3;
      int d0 = t * 32 + ((q ^ ((p >> 1) & 3)) << 3);   // source dims (inverse of read involution)
      int node;
      if (tl == 0)      node = (p <= 8) ? (row0 - 9 + p) : (row0 + 32);
      else if (tl == 1) node = row0 + p;
      else              node = row0 + 16 + p;
      node = node < 0 ? 0 : (node >= NODES ? NODES - 1 : node);
      int n = node % NN;
      float f[14];
      const float2* nf2 = (const float2*)(nf + (size_t)node * 10);
#pragma unroll
      for (int i = 0; i < 5; i++) { float2 v = nf2[i]; f[2 * i] = v.x; f[2 * i + 1] = v.y; }
      f[10] = (n < 7) ? 1.f : 0.f;
      f[11] = (n == 7) ? 1.f : 0.f;
      f[12] = (n == 8) ? 1.f : 0.f;
      f[13] = fabsf((float)(n - 7));
      float acc8[8];
      {
        float4 b0 = *(const float4*)&encb[n * 128 + d0];
        float4 b1 = *(const float4*)&encb[n * 128 + d0 + 4];
        acc8[0] = b0.x; acc8[1] = b0.y; acc8[2] = b0.z; acc8[3] = b0.w;
        acc8[4] = b1.x; acc8[5] = b1.y; acc8[6] = b1.z; acc8[7] = b1.w;
      }
      const float4* w4 = (const float4*)&encW[((size_t)n * 128 + d0) * 14];
#pragma unroll
      for (int j = 0; j < 28; j++) {
        float4 w = w4[j];
        acc8[(4 * j + 0) / 14] = fmaf(f[(4 * j + 0) % 14], w.x, acc8[(4 * j + 0) / 14]);
        acc8[(4 * j + 1) / 14] = fmaf(f[(4 * j + 1) % 14], w.y, acc8[(4 * j + 1) / 14]);
        acc8[(4 * j + 2) / 14] = fmaf(f[(4 * j + 2) % 14], w.z, acc8[(4 * j + 2) / 14]);
        acc8[(4 * j + 3) / 14] = fmaf(f[(4 * j + 3) % 14], w.w, acc8[(4 * j + 3) / 14]);
      }
      half8 o;
#pragma unroll
      for (int j = 0; j < 8; j++) o[j] = (_Float16)acc8[j];
      *(half8*)(Ald + c * 512 + p * 32 + q * 8) = o;
    }
  } else {
    int p = lane >> 2;                                  // row within tile
    int gnode = (p <= 8) ? (row0 - 9 + p) : (row0 + 32);
    gnode = gnode < 0 ? 0 : (gnode >= NODES ? NODES - 1 : gnode);
    int on0 = row0 + p;
    int on1 = row0 + 16 + p; on1 = on1 >= NODES ? NODES - 1 : on1;
#pragma unroll
    for (int i = 0; i < 3; i++) {
      int c = wv + i * 8;                               // chunk id = t*3 + tl
      if (c < 3 * NK) {                                 // wave-uniform branch
        int t = c / 3, tl = c - t * 3;
        int node = (tl == 0) ? gnode : ((tl == 1) ? on0 : on1);
        gl_lds16(Xin + (size_t)node * LDX + t * 32 + bchunk * 8, Ald + c * 512);
      }
    }
  }
  __syncthreads();             // drains own gl_lds + A/nfl visible to all waves

#pragma unroll
  for (int t = 0; t < NK; t++) {
    const bool more = (t + 1 < NK);             // compile-time under full unroll
    const int kn = (t + 1) << 5;                // folds into load immediates
    // A fragments from LDS — issue BEFORE w1 so ds_read latency hides under the wait
    const _Float16* abase = Ald + (t * 3) * 512 + mrow * 32 + rchunk * 8;
    half8 a0 = *(const half8*)abase;            // gather tile
    half8 a1 = *(const half8*)(abase + 512);    // own rows row0..+15
    half8 a2 = *(const half8*)(abase + 1024);   // own rows row0+16..+31
    SB0();
    asm volatile("s_waitcnt vmcnt(4)" ::: "memory");   // L_t landed (B-only queue)
    SB0();
    {  // L group (6 MFMA)
      half8 b0 = *(const half8*)&ring[(0 * 16 + mrow) * 32 + rchunk * 8];
      half8 b1 = *(const half8*)&ring[(1 * 16 + mrow) * 32 + rchunk * 8];
      accL[0][0] = MFMA16(a0, b0, accL[0][0]);
      accL[0][1] = MFMA16(a0, b1, accL[0][1]);
      accL[1][0] = MFMA16(a1, b0, accL[1][0]);
      accL[1][1] = MFMA16(a1, b1, accL[1][1]);
      accL[2][0] = MFMA16(a2, b0, accL[2][0]);
      accL[2][1] = MFMA16(a2, b1, accL[2][1]);
    }
    SB0();
    if (more) { gl_lds16(lsrc + kn, ring); gl_lds16(lsrc2 + kn, ring + 512); }
    SB0();
    if (more) asm volatile("s_waitcnt vmcnt(4)" ::: "memory");   // R_t landed
    else      asm volatile("s_waitcnt vmcnt(2)" ::: "memory");
    SB0();
    {  // R group (4 MFMA) — own tiles
      const _Float16* bb = ring + 1024;
      half8 b0 = *(const half8*)&bb[(0 * 16 + mrow) * 32 + rchunk * 8];
      half8 b1 = *(const half8*)&bb[(1 * 16 + mrow) * 32 + rchunk * 8];
      accR[0][0] = MFMA16(a1, b0, accR[0][0]);
      accR[1][0] = MFMA16(a2, b0, accR[1][0]);
      accR[0][1] = MFMA16(a1, b1, accR[0][1]);
      accR[1][1] = MFMA16(a2, b1, accR[1][1]);
    }
    SB0();
    if (more) { gl_lds16(rsrc + kn, ring + 1024); gl_lds16(rsrc2 + kn, ring + 1536); }
    SB0();
    if (more) asm volatile("s_waitcnt vmcnt(4)" ::: "memory");   // S_t landed
    else      asm volatile("s_waitcnt vmcnt(0)" ::: "memory");
    SB0();
    {  // S group (4 MFMA) — own tiles
      const _Float16* bb = ring + 2048;
      half8 b0 = *(const half8*)&bb[(0 * 16 + mrow) * 32 + rchunk * 8];
      half8 b1 = *(const half8*)&bb[(1 * 16 + mrow) * 32 + rchunk * 8];
      accS[0][0] = MFMA16(a1, b0, accS[0][0]);
      accS[1][0] = MFMA16(a2, b0, accS[1][0]);
      accS[0][1] = MFMA16(a1, b1, accS[0][1]);
      accS[1][1] = MFMA16(a2, b1, accS[1][1]);
    }
    SB0();
    if (more) { gl_lds16(ssrc + kn, ring + 2048); gl_lds16(ssrc2 + kn, ring + 2560); }
    SB0();
  }

  __syncthreads();                     // loop region dead; xl/epi/epi2 overlay it

  // ---- epilogue writes: accL(+lb) -> xl (scattered), accR(+rb) -> epi, accS(+sb) -> epi2 ----
  {
    int quad_ = lane >> 4, mrow_ = lane & 15;
#pragma unroll
    for (int tl = 0; tl < 3; tl++)
#pragma unroll
      for (int ct = 0; ct < 2; ct++) {
        int col = wv * 32 + ct * 16 + mrow_;
        float bs = lb[col];
#pragma unroll
        for (int r = 0; r < 4; r++) {
          int p = quad_ * 4 + r;       // output position within tile = A row index
          int xlrow;
          if (tl == 0) xlrow = (p <= 8) ? (p + 7) : ((p == 9) ? 48 : 49);  // 49 = scratch
          else         xlrow = tl * 16 + p;      // tl=1 -> 16..31, tl=2 -> 32..47
          sh.s.xl[xlrow][col] = f2h(accL[tl][ct][r] + bs);
        }
      }
#pragma unroll
    for (int rt = 0; rt < 2; rt++)
#pragma unroll
      for (int ct = 0; ct < 2; ct++) {
        int col = wv * 32 + ct * 16 + mrow_;
        float bsr = rb[col];
        float bss = sb[col];
#pragma unroll
        for (int r = 0; r < 4; r++) {
          int row = rt * 16 + quad_ * 4 + r;
          sh.s.epi[row][col]  = f2h(accR[rt][ct][r] + bsr);
          sh.s.epi2[row][col] = f2h(accS[rt][ct][r] + bss);
        }
      }
  }
  __syncthreads();

  // ---- edge phase: logits + softmax + aggregation; epi2 <- AGG + XO (pre-LN) ----
  {
    int g = lane >> 4;          // wave handles row r = wv*4 + g
    int l = lane & 15;          // 16-channel slab per lane
    int ch0 = l << 4;
    half8 att_lo = *(const half8*)&atth[ch0];
    half8 att_hi = *(const half8*)&atth[ch0 + 8];
    half8 ew0l, ew1l, ew2l, ew0h, ew1h, ew2h;
#pragma unroll
    for (int j = 0; j < 8; j++) {
      ew0l[j] = ewh[(ch0 + j) * 3 + 0];      ew0h[j] = ewh[(ch0 + 8 + j) * 3 + 0];
      ew1l[j] = ewh[(ch0 + j) * 3 + 1];      ew1h[j] = ewh[(ch0 + 8 + j) * 3 + 1];
      ew2l[j] = ewh[(ch0 + j) * 3 + 2];      ew2h[j] = ewh[(ch0 + 8 + j) * 3 + 2];
    }
    float f0 = fill[0], f1 = fill[1], f2 = fill[2];
    int r = wv * 4 + g;
    int v = row0 + r;
    int n = v % NN;
    int t = (v / NN) & 63;
    int srcs[4]  = { v, (n > 0) ? v - 1 : v, (n < NN - 1) ? v + 1 : v, (t > 0) ? v - NN : v };
    int sidx[4]  = { r + 9, (n > 0) ? r + 8 : r + 9, (n < NN - 1) ? r + 10 : r + 9,
                     (t > 0) ? r : r + 9 };
    bool valid[4] = { true, n > 0, n < NN - 1, t > 0 };
    float px = nfl[r + 9][0];
    float py = nfl[r + 9][1];
    float pz = nfl[r + 9][2];
    _Float16* erow  = (_Float16*)sh.s.epi[r];
    _Float16* e2row = (_Float16*)sh.s.epi2[r];
    half8 xr_lo = *(const half8*)&erow[ch0];
    half8 xr_hi = *(const half8*)&erow[ch0 + 8];
    half8 xls[4][2];
    float lg[4];
#pragma unroll
    for (int e = 0; e < 4; e++) {
      int s = srcs[e];
      float a0, a1, a2;
      if (e == 0) { a0 = f0; a1 = f1; a2 = f2; }
      else {
        a0 = px - nfl[sidx[e]][0];
        a1 = py - nfl[sidx[e]][1];
        a2 = pz - nfl[sidx[e]][2];
      }
      _Float16 h0 = (_Float16)a0, h1 = (_Float16)a1, h2 = (_Float16)a2;
      const _Float16* xrow = (const _Float16*)sh.s.xl[s - row0 + 16];   // indices 7..48
      xls[e][0] = *(const half8*)&xrow[ch0];
      xls[e][1] = *(const half8*)&xrow[ch0 + 8];
      half8 mlo = (xr_lo + xls[e][0]) + (ew0l * h0 + ew1l * h1 + ew2l * h2);
      half8 mhi = (xr_hi + xls[e][1]) + (ew0h * h0 + ew1h * h1 + ew2h * h2);
      mlo = __builtin_elementwise_max(mlo, mlo * (_Float16)0.2f);   // leaky 0.2 exact
      mhi = __builtin_elementwise_max(mhi, mhi * (_Float16)0.2f);
      float p = 0.f;
      p = DOT2(D2(mlo, 0), D2(att_lo, 0), p);
      p = DOT2(D2(mlo, 1), D2(att_lo, 1), p);
      p = DOT2(D2(mlo, 2), D2(att_lo, 2), p);
      p = DOT2(D2(mlo, 3), D2(att_lo, 3), p);
      p = DOT2(D2(mhi, 0), D2(att_hi, 0), p);
      p = DOT2(D2(mhi, 1), D2(att_hi, 1), p);
      p = DOT2(D2(mhi, 2), D2(att_hi, 2), p);
      p = DOT2(D2(mhi, 3), D2(att_hi, 3), p);
      p += __shfl_xor(p, 1);        // head spans 4 lanes (64 ch)
      p += __shfl_xor(p, 2);
      lg[e] = valid[e] ? p : -1e30f;
    }
    float mx = fmaxf(fmaxf(lg[0], lg[1]), fmaxf(lg[2], lg[3]));
    float w0 = __expf(lg[0] - mx), w1 = __expf(lg[1] - mx);
    float w2 = __expf(lg[2] - mx), w3 = __expf(lg[3] - mx);
    float inv = 1.f / (w0 + w1 + w2 + w3);
    float wv4[4] = { w0, w1, w2, w3 };
    half8 agg_lo = *(const half8*)&e2row[ch0];       // start from XO(+sb)
    half8 agg_hi = *(const half8*)&e2row[ch0 + 8];
#pragma unroll
    for (int e = 0; e < 4; e++) {
      _Float16 wh = (_Float16)(wv4[e] * inv);   // invalid edges: exactly 0
      agg_lo = agg_lo + xls[e][0] * wh;
      agg_hi = agg_hi + xls[e][1] * wh;
    }
    // in-place: this lane is the only reader/writer of this slab
    *(half8*)&e2row[ch0] = agg_lo;
    *(half8*)&e2row[ch0 + 8] = agg_hi;
  }
  __syncthreads();                      // pre-LN values visible to all waves

  // ---- LN + SiLU (+ pool for POOL layer) ----
  if constexpr (!POOL) {
    // edge-phase layout: lane = (row-of-4, 16-ch slab); 16-lane-group reductions (4 shfl steps)
    int g = lane >> 4;
    int r = wv * 4 + g;
    int v = row0 + r;
    int ch0 = (lane & 15) << 4;
    const _Float16* e2row = (const _Float16*)sh.s.epi2[r];
    half8 xlo = *(const half8*)&e2row[ch0];
    half8 xhi = *(const half8*)&e2row[ch0 + 8];
    float xv[16];
#pragma unroll
    for (int i = 0; i < 8; i++) { xv[i] = (float)xlo[i]; xv[8 + i] = (float)xhi[i]; }
    float s1 = 0.f;
#pragma unroll
    for (int i = 0; i < 16; i++) s1 += xv[i];
    s1 += __shfl_xor(s1, 1); s1 += __shfl_xor(s1, 2);
    s1 += __shfl_xor(s1, 4); s1 += __shfl_xor(s1, 8);
    float mu = s1 * (1.f / 256.f);
    float s2 = 0.f;
#pragma unroll
    for (int i = 0; i < 16; i++) { float d = xv[i] - mu; s2 = fmaf(d, d, s2); }
    s2 += __shfl_xor(s2, 1); s2 += __shfl_xor(s2, 2);
    s2 += __shfl_xor(s2, 4); s2 += __shfl_xor(s2, 8);
    float rs = rsqrtf(s2 * (1.f / 256.f) + 1e-5f);
    half8 olo, ohi;
#pragma unroll
    for (int i = 0; i < 16; i++) {
      float gmv = gamma[ch0 + i], btv = beta[ch0 + i];
      float y = (xv[i] - mu) * rs * gmv + btv;
      float z = y * (1.f / (1.f + __expf(-y)));   // SiLU
      if (i < 8) olo[i] = (_Float16)z; else ohi[i - 8] = (_Float16)z;
    }
    *(half8*)&Xout[(size_t)v * LDX + ch0] = olo;
    *(half8*)&Xout[(size_t)v * LDX + ch0 + 8] = ohi;
  } else {
    // pool layer: full-wave LN (proven), no Xout store, pool via pacc + atomics
    int cc = lane << 2;
    float gm[4], bt[4];
#pragma unroll
    for (int i = 0; i < 4; i++) { gm[i] = gamma[cc + i]; bt[i] = beta[cc + i]; }
    float psum[4] = { 0.f, 0.f, 0.f, 0.f };
    for (int k = 0; k < 4; k++) {
      int r = wv * 4 + k;
      const _Float16* e2row = (const _Float16*)sh.s.epi2[r];
      half4 x4 = *(const half4*)&e2row[cc];
      float xv[4] = { (float)x4[0], (float)x4[1], (float)x4[2], (float)x4[3] };
      float s1 = xv[0] + xv[1] + xv[2] + xv[3];
#pragma unroll
      for (int off = 1; off < 64; off <<= 1) s1 += __shfl_xor(s1, off);
      float mu = s1 * (1.f / 256.f);
      float s2 = 0.f;
#pragma unroll
      for (int i = 0; i < 4; i++) { float d = xv[i] - mu; s2 = fmaf(d, d, s2); }
#pragma unroll
      for (int off = 1; off < 64; off <<= 1) s2 += __shfl_xor(s2, off);
      float rs = rsqrtf(s2 * (1.f / 256.f) + 1e-5f);
#pragma unroll
      for (int i = 0; i < 4; i++) {
        float y = (xv[i] - mu) * rs * gm[i] + bt[i];
        float z = y * (1.f / (1.f + __expf(-y)));   // SiLU
        psum[i] += z;
      }
    }
    __syncthreads();                 // epi2 reads done; pacc overlays loop region (dead)
#pragma unroll
    for (int i = 0; i < 4; i++) sh.pacc[wv][cc + i] = psum[i];
    __syncthreads();
    if (wv == 0) {
      int b = row0 / 576;            // 576 = 9*64: block fully within one batch
#pragma unroll
      for (int i = 0; i < 4; i++) {
        float s = 0.f;
#pragma unroll
        for (int w = 0; w < 8; w++) s += sh.pacc[w][cc + i];
        atomicAdd(&pool_out[b * 256 + cc + i], s * (1.f / 576.f));
      }
    }
  }
}

extern "C" void kernel_launch(void* const* d_in, const int* in_sizes, int n_in,
                              void* d_out, int out_size, void* d_ws, size_t ws_size,
                              hipStream_t stream) {
  static const int kSize[NARR] = {
    737280, 16128, 1152,
    32768, 256, 32768, 256, 256, 768, 32768, 256, 256, 256,   // layer 0 (K=128)
    65536, 256, 65536, 256, 256, 768, 65536, 256, 256, 256,   // layer 1 (K=256)
    65536, 256, 65536, 256, 256, 768, 65536, 256, 256, 256    // layer 2 (K=256)
  };
  if (n_in != NARR || out_size != BB * 256) return;
  for (int i = 0; i < NARR; i++) if (in_sizes[i] != kSize[i]) return;

  CvtArgs ca;
  int off = 0;
  for (int i = 0; i < NARR; i++) { ca.src[i] = d_in[i]; ca.size[i] = kSize[i]; ca.off[i] = off; off += kSize[i]; }
  const int PRM_ELEMS = off;   // 1,252,992

  const size_t OFF_FLAG = 0;
  const size_t OFF_FILL = 16;
  const size_t OFF_PRM  = 256;
  const size_t OFF_PRMH = OFF_PRM + (size_t)PRM_ELEMS * 4;     // f16 shadow
  const size_t OFF_X0   = OFF_PRMH + (size_t)PRM_ELEMS * 2;    // X ping
  const size_t OFF_X1   = OFF_X0 + (size_t)NODES * LDX * 2;    // X pong
  const size_t NEED     = OFF_X1 + (size_t)NODES * LDX * 2;    // ~83 MiB
  if (ws_size < NEED) return;

  char* ws = (char*)d_ws;
  float*     flag = (float*)(ws + OFF_FLAG);
  float*     fill = (float*)(ws + OFF_FILL);
  float*     prm  = (float*)(ws + OFF_PRM);
  _Float16*  prmh = (_Float16*)(ws + OFF_PRMH);
  _Float16*  X0   = (_Float16*)(ws + OFF_X0);
  _Float16*  X1   = (_Float16*)(ws + OFF_X1);

  hipMemsetAsync(d_out, 0, (size_t)out_size * 4, stream);   // pool accumulator
  detect_fill_kernel<<<1, 256, 0, stream>>>((const unsigned short*)d_in[0], flag, fill);
  convert_kernel<<<dim3(128, NARR), 256, 0, stream>>>(ca, flag, prm, prmh);

  const float* nf   = prm + ca.off[0];
  const float* encW = prm + ca.off[1];
  const float* encb = prm + ca.off[2];

  for (int L = 0; L < 3; L++) {
    const _Float16* lWh = prmh + ca.off[3 + L * 10 + 0];
    const float*    lb  = prm  + ca.off[3 + L * 10 + 1];
    const _Float16* rWh = prmh + ca.off[3 + L * 10 + 2];
    const float*    rb  = prm  + ca.off[3 + L * 10 + 3];
    const _Float16* atth= prmh + ca.off[3 + L * 10 + 4];
    const _Float16* ewhp= prmh + ca.off[3 + L * 10 + 5];
    const _Float16* sWh = prmh + ca.off[3 + L * 10 + 6];
    const float*    sb  = prm  + ca.off[3 + L * 10 + 7];
    const float*    g   = prm  + ca.off[3 + L * 10 + 8];
    const float*    b   = prm  + ca.off[3 + L * 10 + 9];
    if (L == 0)
      fused3_kernel<128, true, false><<<NODES / 32, 512, 0, stream>>>(
          X1 /*unused*/, X0, lWh, lb, rWh, rb, sWh, sb, nf, fill, atth, ewhp, g, b,
          (float*)d_out, encW, encb);
    else if (L == 1)
      fused3_kernel<256, false, false><<<NODES / 32, 512, 0, stream>>>(
          X0, X1, lWh, lb, rWh, rb, sWh, sb, nf, fill, atth, ewhp, g, b,
          (float*)d_out, nullptr, nullptr);
    else
      fused3_kernel<256, false, true><<<NODES / 32, 512, 0, stream>>>(
          X1, X0, lWh, lb, rWh, rb, sWh, sb, nf, fill, atth, ewhp, g, b,
          (float*)d_out, nullptr, nullptr);
  }
}